// Round 1
// baseline (1021.065 us; speedup 1.0000x reference)
//
#include <hip/hip_runtime.h>
#include <hip/hip_bf16.h>
#include <stdint.h>

#define TOKENS 4096
#define DDIM 1024
#define FDIM 4096
#define NEXP 8

typedef __attribute__((ext_vector_type(4))) float f32x4;
typedef __attribute__((ext_vector_type(8))) short short8;

__device__ __forceinline__ unsigned short f2bf(float f) {
    union { float f; uint32_t u; } v; v.f = f;
    uint32_t u = v.u;
    return (unsigned short)((u + 0x7fff + ((u >> 16) & 1)) >> 16);
}

// ---------------- X f32 -> bf16 ----------------
__global__ __launch_bounds__(256) void cvt_x(const float* __restrict__ x,
                                             unsigned short* __restrict__ xb, int n) {
    int i = (blockIdx.x * 256 + threadIdx.x) * 8;
    if (i >= n) return;
    float4 a = *(const float4*)(x + i);
    float4 b = *(const float4*)(x + i + 4);
    short8 o;
    o[0] = f2bf(a.x); o[1] = f2bf(a.y); o[2] = f2bf(a.z); o[3] = f2bf(a.w);
    o[4] = f2bf(b.x); o[5] = f2bf(b.y); o[6] = f2bf(b.z); o[7] = f2bf(b.w);
    *(short8*)(xb + i) = o;
}

// ------------- transpose + cvt: in [E][R][C] f32 -> out [E][C][R] bf16 -------------
__global__ __launch_bounds__(256) void transpose_cvt(const float* __restrict__ in,
                                                     unsigned short* __restrict__ out,
                                                     int R, int C) {
    __shared__ float tile[32][33];
    int e = blockIdx.z;
    int r0 = blockIdx.y * 32, c0 = blockIdx.x * 32;
    const float* src = in + (size_t)e * R * C;
    unsigned short* dst = out + (size_t)e * R * C;
    int t = threadIdx.x;
    int rr = t >> 3;          // 0..31
    int cc = (t & 7) * 4;     // 0,4,...,28
    float4 v = *(const float4*)(src + (size_t)(r0 + rr) * C + c0 + cc);
    tile[rr][cc + 0] = v.x; tile[rr][cc + 1] = v.y;
    tile[rr][cc + 2] = v.z; tile[rr][cc + 3] = v.w;
    __syncthreads();
    int oc = rr;              // out row (c index)
    int orr = cc;             // out col chunk (r index)
    ushort4 o;
    o.x = f2bf(tile[orr + 0][oc]);
    o.y = f2bf(tile[orr + 1][oc]);
    o.z = f2bf(tile[orr + 2][oc]);
    o.w = f2bf(tile[orr + 3][oc]);
    *(ushort4*)(dst + (size_t)(c0 + oc) * R + r0 + orr) = o;
}

// ---------------- router: top-2 of 8 logits, build expert lists ----------------
__global__ __launch_bounds__(256) void router(const float* __restrict__ x,
                                              const float* __restrict__ wr,
                                              int* __restrict__ cnt,
                                              int* __restrict__ list) {
    __shared__ float wl[NEXP * DDIM];   // 32 KB
    int t = threadIdx.x;
    for (int i = t; i < NEXP * DDIM; i += 256) wl[i] = wr[i];
    __syncthreads();
    int tok = blockIdx.x * 4 + (t >> 6);
    int lane = t & 63;
    float acc[NEXP];
#pragma unroll
    for (int e = 0; e < NEXP; e++) acc[e] = 0.f;
    const float* xr = x + (size_t)tok * DDIM;
    for (int d = lane; d < DDIM; d += 64) {
        float xv = xr[d];
#pragma unroll
        for (int e = 0; e < NEXP; e++) acc[e] += xv * wl[e * DDIM + d];
    }
#pragma unroll
    for (int e = 0; e < NEXP; e++) {
#pragma unroll
        for (int off = 32; off; off >>= 1) acc[e] += __shfl_xor(acc[e], off);
    }
    if (lane == 0) {
        int e1 = 0; float v1 = acc[0];
        for (int e = 1; e < NEXP; e++) if (acc[e] > v1) { v1 = acc[e]; e1 = e; }
        int e2 = -1; float v2 = -1e30f;
        for (int e = 0; e < NEXP; e++) if (e != e1 && acc[e] > v2) { v2 = acc[e]; e2 = e; }
        int p1 = atomicAdd(&cnt[e1], 1);
        list[e1 * TOKENS + p1] = tok;
        int p2 = atomicAdd(&cnt[e2], 1);
        list[e2 * TOKENS + p2] = tok;
    }
}

__global__ void prefix(const int* __restrict__ cnt, int* __restrict__ off) {
    if (threadIdx.x == 0) {
        int s = 0;
        for (int e = 0; e < NEXP; e++) { off[e] = s; s += cnt[e]; }
    }
}

// ---------------- grouped GEMM: C[M,N] = A[M,K] * Wt[e][N,K]^T ----------------
// 128x128 tile, 4 waves (2x2), 16x16x32 bf16 MFMA, BK=32, global_load_lds staging.
template <bool GATHER_A, bool SILU, bool ATOMIC_OUT>
__global__ __launch_bounds__(256) void gemm_moe(
    const unsigned short* __restrict__ Abase,  // GATHER: Xb [TOKENS][KD]; else H [8192][KD]
    const unsigned short* __restrict__ Wt,     // [E][NDIM][KD] bf16 (K-contiguous)
    const int* __restrict__ cnt, const int* __restrict__ off,
    const int* __restrict__ list,
    unsigned short* __restrict__ Hout,         // SILU path out (bf16, stride NDIM)
    float* __restrict__ Yout,                  // atomic path out (f32, stride NDIM)
    int KD, int NDIM) {
    __shared__ alignas(16) unsigned short As[128 * 32];
    __shared__ alignas(16) unsigned short Bs[128 * 32];

    const int MT = TOKENS / 128;  // 32
    int e = blockIdx.x / MT;
    int mtile = blockIdx.x % MT;
    int n_e = cnt[e];
    int m0 = mtile * 128;
    if (m0 >= n_e) return;
    int base = off[e];
    int n0 = blockIdx.y * 128;

    int t = threadIdx.x;
    int lane = t & 63;
    int wid = t >> 6;
    int wm = wid >> 1, wn = wid & 1;

    // staging source pointers: 2 16-byte chunks per thread per tile
    const unsigned short* asrc[2];
    const unsigned short* bsrc[2];
#pragma unroll
    for (int i = 0; i < 2; i++) {
        int c = i * 256 + t;
        int row = c >> 2;         // 0..127
        int kc = (c & 3) * 8;     // element offset within BK=32
        int mrow = m0 + row; if (mrow > n_e - 1) mrow = n_e - 1;
        size_t arow;
        if (GATHER_A) arow = (size_t)list[e * TOKENS + mrow];
        else          arow = (size_t)(base + mrow);
        asrc[i] = Abase + arow * (size_t)KD + kc;
        bsrc[i] = Wt + ((size_t)e * NDIM + n0 + row) * (size_t)KD + kc;
    }

    f32x4 acc[4][4];
#pragma unroll
    for (int i = 0; i < 4; i++)
#pragma unroll
        for (int j = 0; j < 4; j++) acc[i][j] = f32x4{0.f, 0.f, 0.f, 0.f};

    int r16 = lane & 15, g = lane >> 4;

    for (int k0 = 0; k0 < KD; k0 += 32) {
#pragma unroll
        for (int i = 0; i < 2; i++) {
            int c = i * 256 + t;
            __builtin_amdgcn_global_load_lds(
                (const __attribute__((address_space(1))) void*)(asrc[i]),
                (__attribute__((address_space(3))) void*)((char*)As + c * 16), 16, 0, 0);
            __builtin_amdgcn_global_load_lds(
                (const __attribute__((address_space(1))) void*)(bsrc[i]),
                (__attribute__((address_space(3))) void*)((char*)Bs + c * 16), 16, 0, 0);
            asrc[i] += 32; bsrc[i] += 32;
        }
        __syncthreads();
        short8 a[4], b[4];
#pragma unroll
        for (int i = 0; i < 4; i++) {
            a[i] = *(const short8*)&As[(wm * 64 + i * 16 + r16) * 32 + g * 8];
            b[i] = *(const short8*)&Bs[(wn * 64 + i * 16 + r16) * 32 + g * 8];
        }
#pragma unroll
        for (int i = 0; i < 4; i++)
#pragma unroll
            for (int j = 0; j < 4; j++)
                acc[i][j] = __builtin_amdgcn_mfma_f32_16x16x32_bf16(a[i], b[j], acc[i][j], 0, 0, 0);
        __syncthreads();
    }

    // epilogue: C/D layout col = lane&15, row = (lane>>4)*4 + reg
#pragma unroll
    for (int i = 0; i < 4; i++) {
#pragma unroll
        for (int j = 0; j < 4; j++) {
#pragma unroll
            for (int q = 0; q < 4; q++) {
                int lr = wm * 64 + i * 16 + g * 4 + q;
                if (m0 + lr < n_e) {
                    int col = n0 + wn * 64 + j * 16 + r16;
                    float v = acc[i][j][q];
                    if (SILU) {
                        v = v / (1.f + __expf(-v));
                        Hout[(size_t)(base + m0 + lr) * NDIM + col] = f2bf(v);
                    } else {
                        int tok = list[e * TOKENS + m0 + lr];
                        atomicAdd(&Yout[(size_t)tok * NDIM + col], v);
                    }
                }
            }
        }
    }
}

extern "C" void kernel_launch(void* const* d_in, const int* in_sizes, int n_in,
                              void* d_out, int out_size, void* d_ws, size_t ws_size,
                              hipStream_t stream) {
    const float* X  = (const float*)d_in[0];
    const float* Wr = (const float*)d_in[1];
    const float* W1 = (const float*)d_in[2];
    const float* W2 = (const float*)d_in[3];
    float* Y = (float*)d_out;

    char* ws = (char*)d_ws;
    int* cnt  = (int*)(ws + 0);
    int* off  = (int*)(ws + 128);
    int* list = (int*)(ws + 1024);                               // 128 KB
    unsigned short* Xb = (unsigned short*)(ws + (1ull << 20));   // 8 MB   @ 1 MB
    unsigned short* WT = (unsigned short*)(ws + (16ull << 20));  // 64 MB  @ 16 MB (W1T, then reused for W2T)
    unsigned short* H  = (unsigned short*)(ws + (80ull << 20));  // 64 MB  @ 80 MB  (peak ~144 MB)

    hipMemsetAsync(d_out, 0, (size_t)out_size * sizeof(float), stream);
    hipMemsetAsync(cnt, 0, 32, stream);

    cvt_x<<<TOKENS * DDIM / (256 * 8), 256, 0, stream>>>(X, Xb, TOKENS * DDIM);
    router<<<TOKENS / 4, 256, 0, stream>>>(X, Wr, cnt, list);
    prefix<<<1, 64, 0, stream>>>(cnt, off);

    // W1 [E][D][F] -> W1T [E][F][D] bf16
    transpose_cvt<<<dim3(FDIM / 32, DDIM / 32, NEXP), 256, 0, stream>>>(W1, WT, DDIM, FDIM);
    // Pass A: H[slot][F] = silu(X[tok] @ W1[e])
    gemm_moe<true, true, false><<<dim3(NEXP * 32, FDIM / 128), 256, 0, stream>>>(
        Xb, WT, cnt, off, list, H, nullptr, DDIM, FDIM);

    // W2 [E][F][D] -> W2T [E][D][F] bf16 (reuses WT buffer; W1T dead now)
    transpose_cvt<<<dim3(DDIM / 32, FDIM / 32, NEXP), 256, 0, stream>>>(W2, WT, FDIM, DDIM);
    // Pass B: Y[tok][D] += H[slot] @ W2[e]
    gemm_moe<false, false, true><<<dim3(NEXP * 32, DDIM / 128), 256, 0, stream>>>(
        H, WT, cnt, off, list, nullptr, Y, FDIM, DDIM);
}

// Round 2
// 542.732 us; speedup vs baseline: 1.8813x; 1.8813x over previous
//
#include <hip/hip_runtime.h>
#include <hip/hip_bf16.h>
#include <stdint.h>

#define TOKENS 4096
#define DDIM 1024
#define FDIM 4096
#define NEXP 8
#define BM 128
#define BN 256
#define BK 64
#define MT (TOKENS / BM)   // 32 M-tiles max per expert

typedef __attribute__((ext_vector_type(4))) float f32x4;
typedef __attribute__((ext_vector_type(8))) short short8;

__device__ __forceinline__ unsigned short f2bf(float f) {
    union { float f; uint32_t u; } v; v.f = f;
    uint32_t u = v.u;
    return (unsigned short)((u + 0x7fff + ((u >> 16) & 1)) >> 16);
}

#define BARRIER() asm volatile("s_barrier" ::: "memory")
#define WAIT_VM0() asm volatile("s_waitcnt vmcnt(0)" ::: "memory")
#define GLDS(SRC, DST) __builtin_amdgcn_global_load_lds( \
    (const __attribute__((address_space(1))) void*)(SRC), \
    (__attribute__((address_space(3))) void*)(DST), 16, 0, 0)

// ---------------- X f32 -> bf16 ----------------
__global__ __launch_bounds__(256) void cvt_x(const float* __restrict__ x,
                                             unsigned short* __restrict__ xb, int n) {
    int i = (blockIdx.x * 256 + threadIdx.x) * 8;
    if (i >= n) return;
    float4 a = *(const float4*)(x + i);
    float4 b = *(const float4*)(x + i + 4);
    short8 o;
    o[0] = f2bf(a.x); o[1] = f2bf(a.y); o[2] = f2bf(a.z); o[3] = f2bf(a.w);
    o[4] = f2bf(b.x); o[5] = f2bf(b.y); o[6] = f2bf(b.z); o[7] = f2bf(b.w);
    *(short8*)(xb + i) = o;
}

// ------------- transpose + cvt: in [E][R][C] f32 -> out [E][C][R] bf16 -------------
__global__ __launch_bounds__(256) void transpose_cvt(const float* __restrict__ in,
                                                     unsigned short* __restrict__ out,
                                                     int R, int C) {
    __shared__ float tile[32][33];
    int e = blockIdx.z;
    int r0 = blockIdx.y * 32, c0 = blockIdx.x * 32;
    const float* src = in + (size_t)e * R * C;
    unsigned short* dst = out + (size_t)e * R * C;
    int t = threadIdx.x;
    int rr = t >> 3;
    int cc = (t & 7) * 4;
    float4 v = *(const float4*)(src + (size_t)(r0 + rr) * C + c0 + cc);
    tile[rr][cc + 0] = v.x; tile[rr][cc + 1] = v.y;
    tile[rr][cc + 2] = v.z; tile[rr][cc + 3] = v.w;
    __syncthreads();
    int oc = rr;
    int orr = cc;
    ushort4 o;
    o.x = f2bf(tile[orr + 0][oc]);
    o.y = f2bf(tile[orr + 1][oc]);
    o.z = f2bf(tile[orr + 2][oc]);
    o.w = f2bf(tile[orr + 3][oc]);
    *(ushort4*)(dst + (size_t)(c0 + oc) * R + r0 + orr) = o;
}

// ---------------- router: top-2 of 8 logits, build expert lists ----------------
__global__ __launch_bounds__(256) void router(const float* __restrict__ x,
                                              const float* __restrict__ wr,
                                              int* __restrict__ cnt,
                                              int* __restrict__ list) {
    __shared__ float wl[NEXP * DDIM];
    int t = threadIdx.x;
    for (int i = t; i < NEXP * DDIM; i += 256) wl[i] = wr[i];
    __syncthreads();
    int tok = blockIdx.x * 4 + (t >> 6);
    int lane = t & 63;
    float acc[NEXP];
#pragma unroll
    for (int e = 0; e < NEXP; e++) acc[e] = 0.f;
    const float* xr = x + (size_t)tok * DDIM;
    for (int d = lane; d < DDIM; d += 64) {
        float xv = xr[d];
#pragma unroll
        for (int e = 0; e < NEXP; e++) acc[e] += xv * wl[e * DDIM + d];
    }
#pragma unroll
    for (int e = 0; e < NEXP; e++) {
#pragma unroll
        for (int off = 32; off; off >>= 1) acc[e] += __shfl_xor(acc[e], off);
    }
    if (lane == 0) {
        int e1 = 0; float v1 = acc[0];
        for (int e = 1; e < NEXP; e++) if (acc[e] > v1) { v1 = acc[e]; e1 = e; }
        int e2 = -1; float v2 = -1e30f;
        for (int e = 0; e < NEXP; e++) if (e != e1 && acc[e] > v2) { v2 = acc[e]; e2 = e; }
        int p1 = atomicAdd(&cnt[e1], 1);
        list[e1 * TOKENS + p1] = tok;
        int p2 = atomicAdd(&cnt[e2], 1);
        list[e2 * TOKENS + p2] = tok;
    }
}

__global__ void prefix(const int* __restrict__ cnt, int* __restrict__ off) {
    if (threadIdx.x == 0) {
        int s = 0;
        for (int e = 0; e < NEXP; e++) { off[e] = s; s += cnt[e]; }
    }
}

// ---------------- grouped GEMM, pipelined ----------------
// C[M,N] = A[M,K] * Wt[e][N,K]^T. BM=128 x BN=256 x BK=64, 512 thr (8 waves 2Mx4N),
// double-buffered LDS, 4 phases/K-tile, issue-early prefetch, XOR-swizzled LDS.
template <bool GATHER_A, bool SILU>
__global__ __launch_bounds__(512, 2) void gemm_moe2(
    const unsigned short* __restrict__ Abase,
    const unsigned short* __restrict__ Wt,      // [E][NDIM][KD] bf16
    const int* __restrict__ cnt, const int* __restrict__ off,
    const int* __restrict__ list,
    unsigned short* __restrict__ Hout,          // SILU out, stride NDIM
    float* __restrict__ Yout,                   // atomic out, stride NDIM
    int KD, int NDIM) {
    __shared__ alignas(16) unsigned short As[2][BM * BK];  // 2 x 16 KB
    __shared__ alignas(16) unsigned short Bs[2][BN * BK];  // 2 x 32 KB

    // bijective XCD swizzle (m204)
    int gx = gridDim.x;
    int flat = blockIdx.y * gx + blockIdx.x;
    int nwg = gx * (int)gridDim.y;
    int q = nwg >> 3, r = nwg & 7;
    int xcd = flat & 7, idx = flat >> 3;
    int swz = (xcd < r) ? (xcd * (q + 1) + idx) : (r * (q + 1) + (xcd - r) * q + idx);
    int bx = swz % gx, by = swz / gx;

    int e = bx / MT, mtile = bx % MT;
    int n_e = cnt[e];
    int m0 = mtile * BM;
    if (m0 >= n_e) return;
    int base = off[e];
    int n0 = by * BN;

    int t = threadIdx.x;
    int lane = t & 63;
    int wid = t >> 6;
    int wm = wid >> 2, wn = wid & 3;
    int r16 = lane & 15, g = lane >> 4;

    // ---- staging source pointers (global pre-swizzled: chunk^(row&7)) ----
    const unsigned short* pA[2];
    const unsigned short* pB[4];
    int ldsA[2], ldsB[4];
#pragma unroll
    for (int i = 0; i < 2; i++) {
        int c = i * 512 + t;
        int row = c >> 3, cc = c & 7;
        int arow = m0 + row; if (arow >= n_e) arow = n_e - 1;
        size_t grow = GATHER_A ? (size_t)list[e * TOKENS + arow] : (size_t)(base + arow);
        pA[i] = Abase + grow * (size_t)KD + ((cc ^ (row & 7)) << 3);
        ldsA[i] = c * 16;
    }
#pragma unroll
    for (int i = 0; i < 4; i++) {
        int c = i * 512 + t;
        int row = c >> 3, cc = c & 7;
        pB[i] = Wt + ((size_t)e * NDIM + n0 + row) * (size_t)KD + ((cc ^ (row & 7)) << 3);
        ldsB[i] = c * 16;
    }

    f32x4 acc[4][4];
#pragma unroll
    for (int i = 0; i < 4; i++)
#pragma unroll
        for (int j = 0; j < 4; j++) acc[i][j] = f32x4{0.f, 0.f, 0.f, 0.f};

    // swizzled fragment address (halfword index): row*BK + ((kchunk ^ (row&7))*8)
#define FRAG(TILE, ROW, KC) (*(const short8*)&(TILE)[(ROW) * BK + ((((KC)) ^ ((ROW) & 7)) << 3)])

    // ---- prologue: stage tile 0 into buf 0 ----
#pragma unroll
    for (int i = 0; i < 4; i++) { GLDS(pB[i], (char*)Bs[0] + ldsB[i]); pB[i] += BK; }
#pragma unroll
    for (int i = 0; i < 2; i++) { GLDS(pA[i], (char*)As[0] + ldsA[i]); pA[i] += BK; }
    WAIT_VM0();
    BARRIER();

    const int NT = KD / BK;
    for (int tk = 0; tk < NT; ++tk) {
        const unsigned short* Ac = As[tk & 1];
        const unsigned short* Bc = Bs[tk & 1];
        char* Ad = (char*)As[(tk & 1) ^ 1];
        char* Bd = (char*)Bs[(tk & 1) ^ 1];
        const bool pf = (tk + 1 < NT);

        short8 b0, b1, b2, b3, a0, a1;
        // ---------- phase 0: slab 0, mi {0,1} ----------
        b0 = FRAG(Bc, wn * 64 + 0 * 16 + r16, g);
        b1 = FRAG(Bc, wn * 64 + 1 * 16 + r16, g);
        b2 = FRAG(Bc, wn * 64 + 2 * 16 + r16, g);
        b3 = FRAG(Bc, wn * 64 + 3 * 16 + r16, g);
        a0 = FRAG(Ac, wm * 64 + 0 * 16 + r16, g);
        a1 = FRAG(Ac, wm * 64 + 1 * 16 + r16, g);
        if (pf) { GLDS(pB[0], Bd + ldsB[0]); pB[0] += BK; GLDS(pB[1], Bd + ldsB[1]); pB[1] += BK; }
        BARRIER();
        __builtin_amdgcn_s_setprio(1);
        acc[0][0] = __builtin_amdgcn_mfma_f32_16x16x32_bf16(a0, b0, acc[0][0], 0, 0, 0);
        acc[0][1] = __builtin_amdgcn_mfma_f32_16x16x32_bf16(a0, b1, acc[0][1], 0, 0, 0);
        acc[0][2] = __builtin_amdgcn_mfma_f32_16x16x32_bf16(a0, b2, acc[0][2], 0, 0, 0);
        acc[0][3] = __builtin_amdgcn_mfma_f32_16x16x32_bf16(a0, b3, acc[0][3], 0, 0, 0);
        acc[1][0] = __builtin_amdgcn_mfma_f32_16x16x32_bf16(a1, b0, acc[1][0], 0, 0, 0);
        acc[1][1] = __builtin_amdgcn_mfma_f32_16x16x32_bf16(a1, b1, acc[1][1], 0, 0, 0);
        acc[1][2] = __builtin_amdgcn_mfma_f32_16x16x32_bf16(a1, b2, acc[1][2], 0, 0, 0);
        acc[1][3] = __builtin_amdgcn_mfma_f32_16x16x32_bf16(a1, b3, acc[1][3], 0, 0, 0);
        __builtin_amdgcn_s_setprio(0);
        BARRIER();
        // ---------- phase 1: slab 0, mi {2,3} ----------
        a0 = FRAG(Ac, wm * 64 + 2 * 16 + r16, g);
        a1 = FRAG(Ac, wm * 64 + 3 * 16 + r16, g);
        if (pf) { GLDS(pB[2], Bd + ldsB[2]); pB[2] += BK; GLDS(pB[3], Bd + ldsB[3]); pB[3] += BK; }
        BARRIER();
        __builtin_amdgcn_s_setprio(1);
        acc[2][0] = __builtin_amdgcn_mfma_f32_16x16x32_bf16(a0, b0, acc[2][0], 0, 0, 0);
        acc[2][1] = __builtin_amdgcn_mfma_f32_16x16x32_bf16(a0, b1, acc[2][1], 0, 0, 0);
        acc[2][2] = __builtin_amdgcn_mfma_f32_16x16x32_bf16(a0, b2, acc[2][2], 0, 0, 0);
        acc[2][3] = __builtin_amdgcn_mfma_f32_16x16x32_bf16(a0, b3, acc[2][3], 0, 0, 0);
        acc[3][0] = __builtin_amdgcn_mfma_f32_16x16x32_bf16(a1, b0, acc[3][0], 0, 0, 0);
        acc[3][1] = __builtin_amdgcn_mfma_f32_16x16x32_bf16(a1, b1, acc[3][1], 0, 0, 0);
        acc[3][2] = __builtin_amdgcn_mfma_f32_16x16x32_bf16(a1, b2, acc[3][2], 0, 0, 0);
        acc[3][3] = __builtin_amdgcn_mfma_f32_16x16x32_bf16(a1, b3, acc[3][3], 0, 0, 0);
        __builtin_amdgcn_s_setprio(0);
        BARRIER();
        // ---------- phase 2: slab 1, mi {0,1} ----------
        b0 = FRAG(Bc, wn * 64 + 0 * 16 + r16, 4 + g);
        b1 = FRAG(Bc, wn * 64 + 1 * 16 + r16, 4 + g);
        b2 = FRAG(Bc, wn * 64 + 2 * 16 + r16, 4 + g);
        b3 = FRAG(Bc, wn * 64 + 3 * 16 + r16, 4 + g);
        a0 = FRAG(Ac, wm * 64 + 0 * 16 + r16, 4 + g);
        a1 = FRAG(Ac, wm * 64 + 1 * 16 + r16, 4 + g);
        if (pf) { GLDS(pA[0], Ad + ldsA[0]); pA[0] += BK; GLDS(pA[1], Ad + ldsA[1]); pA[1] += BK; }
        BARRIER();
        __builtin_amdgcn_s_setprio(1);
        acc[0][0] = __builtin_amdgcn_mfma_f32_16x16x32_bf16(a0, b0, acc[0][0], 0, 0, 0);
        acc[0][1] = __builtin_amdgcn_mfma_f32_16x16x32_bf16(a0, b1, acc[0][1], 0, 0, 0);
        acc[0][2] = __builtin_amdgcn_mfma_f32_16x16x32_bf16(a0, b2, acc[0][2], 0, 0, 0);
        acc[0][3] = __builtin_amdgcn_mfma_f32_16x16x32_bf16(a0, b3, acc[0][3], 0, 0, 0);
        acc[1][0] = __builtin_amdgcn_mfma_f32_16x16x32_bf16(a1, b0, acc[1][0], 0, 0, 0);
        acc[1][1] = __builtin_amdgcn_mfma_f32_16x16x32_bf16(a1, b1, acc[1][1], 0, 0, 0);
        acc[1][2] = __builtin_amdgcn_mfma_f32_16x16x32_bf16(a1, b2, acc[1][2], 0, 0, 0);
        acc[1][3] = __builtin_amdgcn_mfma_f32_16x16x32_bf16(a1, b3, acc[1][3], 0, 0, 0);
        __builtin_amdgcn_s_setprio(0);
        BARRIER();
        // ---------- phase 3: slab 1, mi {2,3} ----------
        a0 = FRAG(Ac, wm * 64 + 2 * 16 + r16, 4 + g);
        a1 = FRAG(Ac, wm * 64 + 3 * 16 + r16, 4 + g);
        BARRIER();
        __builtin_amdgcn_s_setprio(1);
        acc[2][0] = __builtin_amdgcn_mfma_f32_16x16x32_bf16(a0, b0, acc[2][0], 0, 0, 0);
        acc[2][1] = __builtin_amdgcn_mfma_f32_16x16x32_bf16(a0, b1, acc[2][1], 0, 0, 0);
        acc[2][2] = __builtin_amdgcn_mfma_f32_16x16x32_bf16(a0, b2, acc[2][2], 0, 0, 0);
        acc[2][3] = __builtin_amdgcn_mfma_f32_16x16x32_bf16(a0, b3, acc[2][3], 0, 0, 0);
        acc[3][0] = __builtin_amdgcn_mfma_f32_16x16x32_bf16(a1, b0, acc[3][0], 0, 0, 0);
        acc[3][1] = __builtin_amdgcn_mfma_f32_16x16x32_bf16(a1, b1, acc[3][1], 0, 0, 0);
        acc[3][2] = __builtin_amdgcn_mfma_f32_16x16x32_bf16(a1, b2, acc[3][2], 0, 0, 0);
        acc[3][3] = __builtin_amdgcn_mfma_f32_16x16x32_bf16(a1, b3, acc[3][3], 0, 0, 0);
        __builtin_amdgcn_s_setprio(0);
        if (pf) WAIT_VM0();   // loads were issued 2-4 phases ago: cheap drain
        BARRIER();
    }
#undef FRAG

    // ---- epilogue: C row = m0 + wm*64 + mi*16 + g*4 + q; col = n0 + wn*64 + nj*16 + r16 ----
#pragma unroll
    for (int mi = 0; mi < 4; ++mi) {
#pragma unroll
        for (int nj = 0; nj < 4; ++nj) {
#pragma unroll
            for (int qq = 0; qq < 4; ++qq) {
                int lr = wm * 64 + mi * 16 + g * 4 + qq;
                if (m0 + lr < n_e) {
                    int col = n0 + wn * 64 + nj * 16 + r16;
                    float v = acc[mi][nj][qq];
                    if (SILU) {
                        v = v / (1.f + __expf(-v));
                        Hout[(size_t)(base + m0 + lr) * NDIM + col] = f2bf(v);
                    } else {
                        int tok = list[e * TOKENS + m0 + lr];
                        atomicAdd(&Yout[(size_t)tok * NDIM + col], v);
                    }
                }
            }
        }
    }
}

extern "C" void kernel_launch(void* const* d_in, const int* in_sizes, int n_in,
                              void* d_out, int out_size, void* d_ws, size_t ws_size,
                              hipStream_t stream) {
    const float* X  = (const float*)d_in[0];
    const float* Wr = (const float*)d_in[1];
    const float* W1 = (const float*)d_in[2];
    const float* W2 = (const float*)d_in[3];
    float* Y = (float*)d_out;

    char* ws = (char*)d_ws;
    int* cnt  = (int*)(ws + 0);
    int* off  = (int*)(ws + 128);
    int* list = (int*)(ws + 1024);                               // 128 KB
    unsigned short* Xb = (unsigned short*)(ws + (1ull << 20));   // 8 MB
    unsigned short* WT = (unsigned short*)(ws + (16ull << 20));  // 64 MB (W1T, then W2T)
    unsigned short* H  = (unsigned short*)(ws + (80ull << 20));  // 64 MB

    hipMemsetAsync(d_out, 0, (size_t)out_size * sizeof(float), stream);
    hipMemsetAsync(cnt, 0, 32, stream);

    cvt_x<<<TOKENS * DDIM / (256 * 8), 256, 0, stream>>>(X, Xb, TOKENS * DDIM);
    router<<<TOKENS / 4, 256, 0, stream>>>(X, Wr, cnt, list);
    prefix<<<1, 64, 0, stream>>>(cnt, off);

    // W1 [E][D][F] -> W1T [E][F][D] bf16
    transpose_cvt<<<dim3(FDIM / 32, DDIM / 32, NEXP), 256, 0, stream>>>(W1, WT, DDIM, FDIM);
    // Pass A: H[slot][F] = silu(X[tok] @ W1[e])
    gemm_moe2<true, true><<<dim3(NEXP * MT, FDIM / BN), 512, 0, stream>>>(
        Xb, WT, cnt, off, list, H, nullptr, DDIM, FDIM);

    // W2 [E][F][D] -> W2T [E][D][F] bf16 (reuses WT)
    transpose_cvt<<<dim3(DDIM / 32, FDIM / 32, NEXP), 256, 0, stream>>>(W2, WT, FDIM, DDIM);
    // Pass B: Y[tok][D] += H[slot] @ W2[e]
    gemm_moe2<false, false><<<dim3(NEXP * MT, DDIM / BN), 512, 0, stream>>>(
        H, WT, cnt, off, list, nullptr, Y, FDIM, DDIM);
}

// Round 3
// 492.079 us; speedup vs baseline: 2.0750x; 1.1029x over previous
//
#include <hip/hip_runtime.h>
#include <hip/hip_bf16.h>
#include <stdint.h>

#define TOKENS 4096
#define DDIM 1024
#define FDIM 4096
#define NEXP 8
#define BM 128
#define BN 128
#define BK 64

typedef __attribute__((ext_vector_type(4))) float f32x4;
typedef __attribute__((ext_vector_type(8))) short short8;

__device__ __forceinline__ unsigned short f2bf(float f) {
    union { float f; uint32_t u; } v; v.f = f;
    uint32_t u = v.u;
    return (unsigned short)((u + 0x7fff + ((u >> 16) & 1)) >> 16);
}

#define BARRIER() asm volatile("s_barrier" ::: "memory")
#define WAIT_VM0() asm volatile("s_waitcnt vmcnt(0)" ::: "memory")
#define GLDS(SRC, DST) __builtin_amdgcn_global_load_lds( \
    (const __attribute__((address_space(1))) void*)(SRC), \
    (__attribute__((address_space(3))) void*)(DST), 16, 0, 0)

// ---------------- X f32 -> bf16 ----------------
__global__ __launch_bounds__(256) void cvt_x(const float* __restrict__ x,
                                             unsigned short* __restrict__ xb, int n) {
    int i = (blockIdx.x * 256 + threadIdx.x) * 8;
    if (i >= n) return;
    float4 a = *(const float4*)(x + i);
    float4 b = *(const float4*)(x + i + 4);
    short8 o;
    o[0] = f2bf(a.x); o[1] = f2bf(a.y); o[2] = f2bf(a.z); o[3] = f2bf(a.w);
    o[4] = f2bf(b.x); o[5] = f2bf(b.y); o[6] = f2bf(b.z); o[7] = f2bf(b.w);
    *(short8*)(xb + i) = o;
}

// ------------- transpose + cvt: in [E][R][C] f32 -> out [E][C][R] bf16 -------------
__global__ __launch_bounds__(256) void transpose_cvt(const float* __restrict__ in,
                                                     unsigned short* __restrict__ out,
                                                     int R, int C) {
    __shared__ float tile[32][33];
    int e = blockIdx.z;
    int r0 = blockIdx.y * 32, c0 = blockIdx.x * 32;
    const float* src = in + (size_t)e * R * C;
    unsigned short* dst = out + (size_t)e * R * C;
    int t = threadIdx.x;
    int rr = t >> 3;
    int cc = (t & 7) * 4;
    float4 v = *(const float4*)(src + (size_t)(r0 + rr) * C + c0 + cc);
    tile[rr][cc + 0] = v.x; tile[rr][cc + 1] = v.y;
    tile[rr][cc + 2] = v.z; tile[rr][cc + 3] = v.w;
    __syncthreads();
    int oc = rr;
    int orr = cc;
    ushort4 o;
    o.x = f2bf(tile[orr + 0][oc]);
    o.y = f2bf(tile[orr + 1][oc]);
    o.z = f2bf(tile[orr + 2][oc]);
    o.w = f2bf(tile[orr + 3][oc]);
    *(ushort4*)(dst + (size_t)(c0 + oc) * R + r0 + orr) = o;
}

// ---------------- router: top-2 of 8 logits, build expert lists ----------------
__global__ __launch_bounds__(256) void router(const float* __restrict__ x,
                                              const float* __restrict__ wr,
                                              int* __restrict__ cnt,
                                              int* __restrict__ list) {
    __shared__ float wl[NEXP * DDIM];
    int t = threadIdx.x;
    for (int i = t; i < NEXP * DDIM; i += 256) wl[i] = wr[i];
    __syncthreads();
    int tok = blockIdx.x * 4 + (t >> 6);
    int lane = t & 63;
    float acc[NEXP];
#pragma unroll
    for (int e = 0; e < NEXP; e++) acc[e] = 0.f;
    const float* xr = x + (size_t)tok * DDIM;
    for (int d = lane; d < DDIM; d += 64) {
        float xv = xr[d];
#pragma unroll
        for (int e = 0; e < NEXP; e++) acc[e] += xv * wl[e * DDIM + d];
    }
#pragma unroll
    for (int e = 0; e < NEXP; e++) {
#pragma unroll
        for (int off = 32; off; off >>= 1) acc[e] += __shfl_xor(acc[e], off);
    }
    if (lane == 0) {
        int e1 = 0; float v1 = acc[0];
        for (int e = 1; e < NEXP; e++) if (acc[e] > v1) { v1 = acc[e]; e1 = e; }
        int e2 = -1; float v2 = -1e30f;
        for (int e = 0; e < NEXP; e++) if (e != e1 && acc[e] > v2) { v2 = acc[e]; e2 = e; }
        int p1 = atomicAdd(&cnt[e1], 1);
        list[e1 * TOKENS + p1] = tok;
        int p2 = atomicAdd(&cnt[e2], 1);
        list[e2 * TOKENS + p2] = tok;
    }
}

// ---------------- setup: offsets, per-pass work bases, totals, counters ----------------
__global__ void setup(const int* __restrict__ cnt, int* __restrict__ off,
                      int* __restrict__ wbA, int* __restrict__ wbB,
                      int* __restrict__ qctr, int* __restrict__ tot) {
    if (threadIdx.x == 0) {
        int s = 0, ta = 0, tb = 0;
        for (int e = 0; e < NEXP; e++) {
            off[e] = s; s += cnt[e];
            wbA[e] = ta; wbB[e] = tb;
            int nt = (cnt[e] + BM - 1) / BM;
            ta += nt * (FDIM / BN);
            tb += nt * (DDIM / BN);
        }
        wbA[NEXP] = ta; wbB[NEXP] = tb;
        tot[0] = ta; tot[1] = tb;
        qctr[0] = 0; qctr[1] = 0;
    }
}

// ---------------- persistent grouped GEMM ----------------
// C[M,N] = A[M,K] * Wt[e][N,K]^T. BM=BN=128, BK=64, 256 thr (4 waves 2x2),
// double-buffered 64 KB LDS (2 blocks/CU), atomic work queue, XOR-swizzled LDS.
template <bool GATHER_A, bool SILU>
__global__ __launch_bounds__(256, 2) void gemm_moe3(
    const unsigned short* __restrict__ Abase,
    const unsigned short* __restrict__ Wt,      // [E][NDIM][KD] bf16
    const int* __restrict__ cnt, const int* __restrict__ off,
    const int* __restrict__ list,
    const int* __restrict__ wbase,              // [NEXP+1] work-item bases
    int* __restrict__ qctr, const int* __restrict__ tot,
    unsigned short* __restrict__ Hout,          // SILU out, stride NDIM
    float* __restrict__ Yout,                   // atomic out, stride NDIM
    int KD, int NDIM) {
    __shared__ alignas(16) unsigned short As[2][BM * BK];  // 2 x 16 KB
    __shared__ alignas(16) unsigned short Bs[2][BN * BK];  // 2 x 16 KB
    __shared__ int wsh;

    int t = threadIdx.x;
    int lane = t & 63;
    int wid = t >> 6;
    int wm = wid >> 1, wn = wid & 1;
    int r16 = lane & 15, g = lane >> 4;
    const int total = *tot;

    // swizzled fragment read (halfword index): row*BK + ((kc ^ (row&7))*8)
#define FRAG(TILE, ROW, KC) (*(const short8*)&(TILE)[(ROW) * BK + ((((KC)) ^ ((ROW) & 7)) << 3)])

    for (;;) {
        if (t == 0) wsh = atomicAdd(qctr, 1);
        __syncthreads();
        int w = wsh;
        if (w >= total) break;

        // ---- decode work item: expert e, by (outer), mtile (inner) ----
        int e = 0;
        while (e < NEXP - 1 && w >= wbase[e + 1]) e++;
        w -= wbase[e];
        int n_e = cnt[e];
        int ntm = (n_e + BM - 1) >> 7;
        int by = w / ntm;
        int mtile = w - by * ntm;
        int m0 = mtile * BM;
        int n0 = by * BN;
        int base = off[e];

        // ---- staging pointers: 4 chunks of 16 B per thread per operand ----
        const unsigned short* pA[4];
        const unsigned short* pB[4];
        int ldsA[4], ldsB[4];
#pragma unroll
        for (int i = 0; i < 4; i++) {
            int c = i * 256 + t;
            int row = c >> 3, cc = c & 7;
            int arow = m0 + row; if (arow >= n_e) arow = n_e - 1;
            size_t grow = GATHER_A ? (size_t)list[e * TOKENS + arow] : (size_t)(base + arow);
            pA[i] = Abase + grow * (size_t)KD + ((cc ^ (row & 7)) << 3);
            ldsA[i] = c * 16;
            pB[i] = Wt + ((size_t)e * NDIM + n0 + row) * (size_t)KD + ((cc ^ (row & 7)) << 3);
            ldsB[i] = c * 16;
        }

        f32x4 acc[4][4];
#pragma unroll
        for (int i = 0; i < 4; i++)
#pragma unroll
            for (int j = 0; j < 4; j++) acc[i][j] = f32x4{0.f, 0.f, 0.f, 0.f};

        // ---- prologue: stage tile 0 into buf 0 ----
#pragma unroll
        for (int i = 0; i < 4; i++) { GLDS(pB[i], (char*)Bs[0] + ldsB[i]); pB[i] += BK; }
#pragma unroll
        for (int i = 0; i < 4; i++) { GLDS(pA[i], (char*)As[0] + ldsA[i]); pA[i] += BK; }
        WAIT_VM0();
        BARRIER();

        const int NT = KD / BK;
        for (int tk = 0; tk < NT; ++tk) {
            const unsigned short* Ac = As[tk & 1];
            const unsigned short* Bc = Bs[tk & 1];
            char* Ad = (char*)As[(tk & 1) ^ 1];
            char* Bd = (char*)Bs[(tk & 1) ^ 1];
            const bool pf = (tk + 1 < NT);

            // issue next-tile stage FIRST (T3: loads in flight across the compute)
            if (pf) {
#pragma unroll
                for (int i = 0; i < 4; i++) { GLDS(pB[i], Bd + ldsB[i]); pB[i] += BK; }
#pragma unroll
                for (int i = 0; i < 4; i++) { GLDS(pA[i], Ad + ldsA[i]); pA[i] += BK; }
            }

            short8 a0, a1, a2, a3, b0, b1, b2, b3;
            // ---- slab 0 (k = 0..31) ----
            a0 = FRAG(Ac, wm * 64 + 0 * 16 + r16, g);
            a1 = FRAG(Ac, wm * 64 + 1 * 16 + r16, g);
            a2 = FRAG(Ac, wm * 64 + 2 * 16 + r16, g);
            a3 = FRAG(Ac, wm * 64 + 3 * 16 + r16, g);
            b0 = FRAG(Bc, wn * 64 + 0 * 16 + r16, g);
            b1 = FRAG(Bc, wn * 64 + 1 * 16 + r16, g);
            b2 = FRAG(Bc, wn * 64 + 2 * 16 + r16, g);
            b3 = FRAG(Bc, wn * 64 + 3 * 16 + r16, g);
            __builtin_amdgcn_s_setprio(1);
            acc[0][0] = __builtin_amdgcn_mfma_f32_16x16x32_bf16(a0, b0, acc[0][0], 0, 0, 0);
            acc[0][1] = __builtin_amdgcn_mfma_f32_16x16x32_bf16(a0, b1, acc[0][1], 0, 0, 0);
            acc[0][2] = __builtin_amdgcn_mfma_f32_16x16x32_bf16(a0, b2, acc[0][2], 0, 0, 0);
            acc[0][3] = __builtin_amdgcn_mfma_f32_16x16x32_bf16(a0, b3, acc[0][3], 0, 0, 0);
            acc[1][0] = __builtin_amdgcn_mfma_f32_16x16x32_bf16(a1, b0, acc[1][0], 0, 0, 0);
            acc[1][1] = __builtin_amdgcn_mfma_f32_16x16x32_bf16(a1, b1, acc[1][1], 0, 0, 0);
            acc[1][2] = __builtin_amdgcn_mfma_f32_16x16x32_bf16(a1, b2, acc[1][2], 0, 0, 0);
            acc[1][3] = __builtin_amdgcn_mfma_f32_16x16x32_bf16(a1, b3, acc[1][3], 0, 0, 0);
            acc[2][0] = __builtin_amdgcn_mfma_f32_16x16x32_bf16(a2, b0, acc[2][0], 0, 0, 0);
            acc[2][1] = __builtin_amdgcn_mfma_f32_16x16x32_bf16(a2, b1, acc[2][1], 0, 0, 0);
            acc[2][2] = __builtin_amdgcn_mfma_f32_16x16x32_bf16(a2, b2, acc[2][2], 0, 0, 0);
            acc[2][3] = __builtin_amdgcn_mfma_f32_16x16x32_bf16(a2, b3, acc[2][3], 0, 0, 0);
            acc[3][0] = __builtin_amdgcn_mfma_f32_16x16x32_bf16(a3, b0, acc[3][0], 0, 0, 0);
            acc[3][1] = __builtin_amdgcn_mfma_f32_16x16x32_bf16(a3, b1, acc[3][1], 0, 0, 0);
            acc[3][2] = __builtin_amdgcn_mfma_f32_16x16x32_bf16(a3, b2, acc[3][2], 0, 0, 0);
            acc[3][3] = __builtin_amdgcn_mfma_f32_16x16x32_bf16(a3, b3, acc[3][3], 0, 0, 0);
            __builtin_amdgcn_s_setprio(0);
            // ---- slab 1 (k = 32..63) ----
            a0 = FRAG(Ac, wm * 64 + 0 * 16 + r16, 4 + g);
            a1 = FRAG(Ac, wm * 64 + 1 * 16 + r16, 4 + g);
            a2 = FRAG(Ac, wm * 64 + 2 * 16 + r16, 4 + g);
            a3 = FRAG(Ac, wm * 64 + 3 * 16 + r16, 4 + g);
            b0 = FRAG(Bc, wn * 64 + 0 * 16 + r16, 4 + g);
            b1 = FRAG(Bc, wn * 64 + 1 * 16 + r16, 4 + g);
            b2 = FRAG(Bc, wn * 64 + 2 * 16 + r16, 4 + g);
            b3 = FRAG(Bc, wn * 64 + 3 * 16 + r16, 4 + g);
            __builtin_amdgcn_s_setprio(1);
            acc[0][0] = __builtin_amdgcn_mfma_f32_16x16x32_bf16(a0, b0, acc[0][0], 0, 0, 0);
            acc[0][1] = __builtin_amdgcn_mfma_f32_16x16x32_bf16(a0, b1, acc[0][1], 0, 0, 0);
            acc[0][2] = __builtin_amdgcn_mfma_f32_16x16x32_bf16(a0, b2, acc[0][2], 0, 0, 0);
            acc[0][3] = __builtin_amdgcn_mfma_f32_16x16x32_bf16(a0, b3, acc[0][3], 0, 0, 0);
            acc[1][0] = __builtin_amdgcn_mfma_f32_16x16x32_bf16(a1, b0, acc[1][0], 0, 0, 0);
            acc[1][1] = __builtin_amdgcn_mfma_f32_16x16x32_bf16(a1, b1, acc[1][1], 0, 0, 0);
            acc[1][2] = __builtin_amdgcn_mfma_f32_16x16x32_bf16(a1, b2, acc[1][2], 0, 0, 0);
            acc[1][3] = __builtin_amdgcn_mfma_f32_16x16x32_bf16(a1, b3, acc[1][3], 0, 0, 0);
            acc[2][0] = __builtin_amdgcn_mfma_f32_16x16x32_bf16(a2, b0, acc[2][0], 0, 0, 0);
            acc[2][1] = __builtin_amdgcn_mfma_f32_16x16x32_bf16(a2, b1, acc[2][1], 0, 0, 0);
            acc[2][2] = __builtin_amdgcn_mfma_f32_16x16x32_bf16(a2, b2, acc[2][2], 0, 0, 0);
            acc[2][3] = __builtin_amdgcn_mfma_f32_16x16x32_bf16(a2, b3, acc[2][3], 0, 0, 0);
            acc[3][0] = __builtin_amdgcn_mfma_f32_16x16x32_bf16(a3, b0, acc[3][0], 0, 0, 0);
            acc[3][1] = __builtin_amdgcn_mfma_f32_16x16x32_bf16(a3, b1, acc[3][1], 0, 0, 0);
            acc[3][2] = __builtin_amdgcn_mfma_f32_16x16x32_bf16(a3, b2, acc[3][2], 0, 0, 0);
            acc[3][3] = __builtin_amdgcn_mfma_f32_16x16x32_bf16(a3, b3, acc[3][3], 0, 0, 0);
            __builtin_amdgcn_s_setprio(0);

            if (pf) WAIT_VM0();
            BARRIER();
        }

        // ---- epilogue ----
#pragma unroll
        for (int mi = 0; mi < 4; ++mi) {
#pragma unroll
            for (int nj = 0; nj < 4; ++nj) {
#pragma unroll
                for (int qq = 0; qq < 4; ++qq) {
                    int lr = wm * 64 + mi * 16 + g * 4 + qq;
                    if (m0 + lr < n_e) {
                        int col = n0 + wn * 64 + nj * 16 + r16;
                        float v = acc[mi][nj][qq];
                        if (SILU) {
                            v = v / (1.f + __expf(-v));
                            Hout[(size_t)(base + m0 + lr) * NDIM + col] = f2bf(v);
                        } else {
                            int tok = list[e * TOKENS + m0 + lr];
                            atomicAdd(&Yout[(size_t)tok * NDIM + col], v);
                        }
                    }
                }
            }
        }
    }
#undef FRAG
}

extern "C" void kernel_launch(void* const* d_in, const int* in_sizes, int n_in,
                              void* d_out, int out_size, void* d_ws, size_t ws_size,
                              hipStream_t stream) {
    const float* X  = (const float*)d_in[0];
    const float* Wr = (const float*)d_in[1];
    const float* W1 = (const float*)d_in[2];
    const float* W2 = (const float*)d_in[3];
    float* Y = (float*)d_out;

    char* ws = (char*)d_ws;
    int* cnt  = (int*)(ws + 0);      // 8
    int* off  = (int*)(ws + 64);     // 8
    int* wbA  = (int*)(ws + 128);    // 9
    int* wbB  = (int*)(ws + 192);    // 9
    int* qctr = (int*)(ws + 256);    // 2
    int* tot  = (int*)(ws + 288);    // 2
    int* list = (int*)(ws + 1024);                               // 128 KB
    unsigned short* Xb = (unsigned short*)(ws + (1ull << 20));   // 8 MB
    unsigned short* WT = (unsigned short*)(ws + (16ull << 20));  // 64 MB (W1T, then W2T)
    unsigned short* H  = (unsigned short*)(ws + (80ull << 20));  // 64 MB

    hipMemsetAsync(d_out, 0, (size_t)out_size * sizeof(float), stream);
    hipMemsetAsync(cnt, 0, 32, stream);

    cvt_x<<<TOKENS * DDIM / (256 * 8), 256, 0, stream>>>(X, Xb, TOKENS * DDIM);
    router<<<TOKENS / 4, 256, 0, stream>>>(X, Wr, cnt, list);
    setup<<<1, 64, 0, stream>>>(cnt, off, wbA, wbB, qctr, tot);

    // W1 [E][D][F] -> W1T [E][F][D] bf16
    transpose_cvt<<<dim3(FDIM / 32, DDIM / 32, NEXP), 256, 0, stream>>>(W1, WT, DDIM, FDIM);
    // Pass A: H[slot][F] = silu(X[tok] @ W1[e])   (persistent, work queue A)
    gemm_moe3<true, true><<<512, 256, 0, stream>>>(
        Xb, WT, cnt, off, list, wbA, qctr + 0, tot + 0, H, nullptr, DDIM, FDIM);

    // W2 [E][F][D] -> W2T [E][D][F] bf16 (reuses WT)
    transpose_cvt<<<dim3(DDIM / 32, FDIM / 32, NEXP), 256, 0, stream>>>(W2, WT, FDIM, DDIM);
    // Pass B: Y[tok][D] += H[slot] @ W2[e]   (persistent, work queue B)
    gemm_moe3<false, false><<<512, 256, 0, stream>>>(
        H, WT, cnt, off, list, wbB, qctr + 1, tot + 1, nullptr, Y, FDIM, DDIM);
}